// Round 6
// baseline (236.030 us; speedup 1.0000x reference)
//
#include <hip/hip_runtime.h>
#include <stdint.h>

// B=4, N=8192, F=64, L=2:  z = x; 2x: z = relu(A @ z @ W_l)  ==  relu(A @ (z @ W_l))
// Pipeline (5 dispatches):
//   zw0:      Zt[c=b*64+g][n] = sum_f x[b,n,f] W0[f,g]            (bf16, K-major)
//   gemm1:    P[s][m][c] (bf16) = sum_{k in s} A[m,k] Zt[c][k]    A read NT f32,
//             cvt->bf16 in-reg, linear ds_write + store Ab bf16 (L3-cached for gemm2)
//   zw1P:     rows = relu(sum_s P[s])  (fused combine);  Zt = rows @ W1
//   gemm2:    P[s][m][c] (bf16) = sum_{k in s} Ab[m,k] Zt[c][k]   (global_load_lds)
//   combineF: out = relu(sum_s P[s])  -> f32 [4][8192][64]
// GEMM geometry (occupancy-first): BM=64 BN=256(=N) BK=32, splitK=8, grid 1024
// (128 m-panels x 8 chunks, s=bid&7 -> per-XCD B K-chunk L2-resident), 256 thr
// (4 waves 1x4, wave tile 64x64, acc 64 VGPR) -> 3 blocks/CU; LDS 40 KiB dbuf,
// single __syncthreads per tile (cross-block TLP hides the drain — r2/r4-proven).
// BK=32 frag reads are bijective per 1KB chunk -> linear LDS, no swizzle, no conflicts.
//
// ws: [0,128Mi) Ab | [128Mi,+4Mi) Zt | [136Mi,+32Mi) P (bf16 [8][8192][256])

#define MK 8192

typedef float f32x4 __attribute__((ext_vector_type(4)));
typedef uint32_t u32x4 __attribute__((ext_vector_type(4)));
typedef uint32_t u32x2 __attribute__((ext_vector_type(2)));
typedef __bf16 bf16x8 __attribute__((ext_vector_type(8)));

__device__ inline uint16_t f2bf(float f) {
  uint32_t u = __builtin_bit_cast(uint32_t, f);
  u += 0x7fffu + ((u >> 16) & 1u);   // RNE (finite randn inputs)
  return (uint16_t)(u >> 16);
}
__device__ inline float bf2f(uint32_t lo16) {
  return __builtin_bit_cast(float, lo16 << 16);
}

#define GLD(src, dstbase)                                                                    \
  __builtin_amdgcn_global_load_lds((const __attribute__((address_space(1))) uint32_t*)(src), \
                                   (__attribute__((address_space(3))) uint32_t*)(dstbase),   \
                                   16, 0, 0)

// ---------------- zw0: Zt = (x @ W0)^T ----------------------------------------------------
__global__ __launch_bounds__(256) void zw0(const float* __restrict__ x,
                                           const float* __restrict__ net,
                                           uint16_t* __restrict__ Zt) {
  __shared__ float Wl[64 * 64];
  __shared__ float rows[64][65];
  const int b = blockIdx.y, n0 = blockIdx.x * 64, tid = threadIdx.x;
  for (int i = tid * 4; i < 4096; i += 1024) {
    f32x4 v = *(const f32x4*)(net + i);
    Wl[i] = v[0]; Wl[i + 1] = v[1]; Wl[i + 2] = v[2]; Wl[i + 3] = v[3];
  }
  const float* src = x + ((uint64_t)b * MK + n0) * 64;
  for (int i = tid * 4; i < 4096; i += 1024) {
    f32x4 v = *(const f32x4*)(src + i);
    int r = i >> 6, f = i & 63;
    rows[r][f] = v[0]; rows[r][f + 1] = v[1]; rows[r][f + 2] = v[2]; rows[r][f + 3] = v[3];
  }
  __syncthreads();
  const int nl = tid & 63, g0 = (tid >> 6) * 16;
  float s[16];
#pragma unroll
  for (int j = 0; j < 16; ++j) s[j] = 0.f;
  for (int f = 0; f < 64; ++f) {
    float rv = rows[nl][f];
#pragma unroll
    for (int j = 0; j < 16; ++j) s[j] = fmaf(rv, Wl[f * 64 + g0 + j], s[j]);
  }
  uint16_t* dst = Zt + (uint64_t)(b * 64 + g0) * MK + n0 + nl;
#pragma unroll
  for (int j = 0; j < 16; ++j) dst[(uint64_t)j * MK] = f2bf(s[j]);
}

// ---------------- gemm1: A nt-f32 -> cvt -> LDS/Ab; P[s](bf16) = A @ Zt^T -----------------
// BM=64 BN=256 BK=32; A reg-staged (f32->bf16), B via global_load_lds; 3 blocks/CU.
__global__ __launch_bounds__(256, 3) void gemm1(const float* __restrict__ Af,
                                                const uint16_t* __restrict__ Bt,
                                                uint16_t* __restrict__ Ab,
                                                uint16_t* __restrict__ P) {
  __shared__ __align__(16) uint16_t As[2][2048];   // [64r][32k] bf16, 4 KB/buf
  __shared__ __align__(16) uint16_t Bs[2][8192];   // [256r][32k] bf16, 16 KB/buf
  const int bid = (int)blockIdx.x;
  const int s = bid & 7, bm = bid >> 3;
  const int row0 = bm * 64, k0 = s * 1024;
  const int tid = threadIdx.x, wid = tid >> 6, lane = tid & 63;

  // A staging: thread t -> row t>>2, k-octet t&3 (8 f32 = 32B = 2 f32x4 NT loads)
  const int ar = tid >> 2, ao = (tid & 3) * 8;
  const float* gA = Af + (uint64_t)(row0 + ar) * MK + k0 + ao;
  uint16_t* AbW = Ab + (uint64_t)(row0 + ar) * MK + k0 + ao;

  // B staging via GLD: wave w chunks 4w..4w+3 (chunk = 16 rows x 32k = 1 KB)
  const int brow = lane >> 2, boct = (lane & 3) * 8;
  const uint16_t* gB[4];
#pragma unroll
  for (int j = 0; j < 4; ++j)
    gB[j] = Bt + (uint64_t)((4 * wid + j) * 16 + brow) * MK + k0 + boct;
  const int lB = 4 * wid * 512;   // ushort index of wave's chunk base

  f32x4 acc[4][4] = {};
  f32x4 rv0, rv1;

  auto loadA = [&](int kt) {
    rv0 = __builtin_nontemporal_load((const f32x4*)(gA + kt));
    rv1 = __builtin_nontemporal_load((const f32x4*)(gA + kt + 4));
  };
  auto stageA = [&](int buf, int kt) {   // cvt + linear ds_write + Ab store
    u32x4 w;
    w[0] = (uint32_t)f2bf(rv0[0]) | ((uint32_t)f2bf(rv0[1]) << 16);
    w[1] = (uint32_t)f2bf(rv0[2]) | ((uint32_t)f2bf(rv0[3]) << 16);
    w[2] = (uint32_t)f2bf(rv1[0]) | ((uint32_t)f2bf(rv1[1]) << 16);
    w[3] = (uint32_t)f2bf(rv1[2]) | ((uint32_t)f2bf(rv1[3]) << 16);
    *(u32x4*)&As[buf][ar * 32 + ao] = w;
    *(u32x4*)(AbW + kt) = w;
  };

  // prologue: tile 0 -> buf 0
  loadA(0);
  stageA(0, 0);
#pragma unroll
  for (int j = 0; j < 4; ++j) GLD(gB[j], &Bs[0][lB + j * 512]);
  __syncthreads();

  int buf = 0;
  for (int t = 0; t < 32; ++t) {
    const int nxt = (t + 1) * 32;
    if (t < 31) {
      loadA(nxt);
#pragma unroll
      for (int j = 0; j < 4; ++j) GLD(gB[j] + nxt, &Bs[buf ^ 1][lB + j * 512]);
    }
    bf16x8 a[4], b[4];
#pragma unroll
    for (int m = 0; m < 4; ++m)
      a[m] = *(const bf16x8*)&As[buf][(m * 16 + (lane & 15)) * 32 + (lane >> 4) * 8];
#pragma unroll
    for (int n = 0; n < 4; ++n)
      b[n] = *(const bf16x8*)&Bs[buf][(wid * 64 + n * 16 + (lane & 15)) * 32 + (lane >> 4) * 8];
#pragma unroll
    for (int m = 0; m < 4; ++m)
#pragma unroll
      for (int n = 0; n < 4; ++n)
        acc[m][n] = __builtin_amdgcn_mfma_f32_16x16x32_bf16(a[m], b[n], acc[m][n], 0, 0, 0);
    if (t < 31) stageA(buf ^ 1, nxt);
    __syncthreads();
    buf ^= 1;
  }

  uint16_t* Pp = P + (uint64_t)s * 2097152;
  const int lr = (lane >> 4) * 4, lc = lane & 15;
#pragma unroll
  for (int m = 0; m < 4; ++m)
#pragma unroll
    for (int n = 0; n < 4; ++n) {
      const int gr = row0 + m * 16 + lr;
      const int gc = wid * 64 + n * 16 + lc;
#pragma unroll
      for (int j = 0; j < 4; ++j)
        Pp[(uint64_t)(gr + j) * 256 + gc] = f2bf(acc[m][n][j]);
    }
}

// ---------------- gemm2: pure bf16 (Ab L3-resident), same geometry, GLD both --------------
__global__ __launch_bounds__(256, 3) void gemm2(const uint16_t* __restrict__ Ab,
                                                const uint16_t* __restrict__ Bt,
                                                uint16_t* __restrict__ P) {
  __shared__ __align__(16) uint16_t As[2][2048];
  __shared__ __align__(16) uint16_t Bs[2][8192];
  const int bid = (int)blockIdx.x;
  const int s = bid & 7, bm = bid >> 3;
  const int row0 = bm * 64, k0 = s * 1024;
  const int tid = threadIdx.x, wid = tid >> 6, lane = tid & 63;

  // wave w: A chunk w (16 rows), B chunks 4w..4w+3; chunk = 16 rows x 32k = 1 KB
  const int crow = lane >> 2, coct = (lane & 3) * 8;
  const uint16_t* gA = Ab + (uint64_t)(row0 + wid * 16 + crow) * MK + k0 + coct;
  const uint16_t* gB[4];
#pragma unroll
  for (int j = 0; j < 4; ++j)
    gB[j] = Bt + (uint64_t)((4 * wid + j) * 16 + crow) * MK + k0 + coct;
  const int lA = wid * 512, lB = 4 * wid * 512;

  f32x4 acc[4][4] = {};

  // prologue
  GLD(gA, &As[0][lA]);
#pragma unroll
  for (int j = 0; j < 4; ++j) GLD(gB[j], &Bs[0][lB + j * 512]);
  __syncthreads();

  int buf = 0;
  for (int t = 0; t < 32; ++t) {
    if (t < 31) {
      const int nxt = (t + 1) * 32;
      GLD(gA + nxt, &As[buf ^ 1][lA]);
#pragma unroll
      for (int j = 0; j < 4; ++j) GLD(gB[j] + nxt, &Bs[buf ^ 1][lB + j * 512]);
    }
    bf16x8 a[4], b[4];
#pragma unroll
    for (int m = 0; m < 4; ++m)
      a[m] = *(const bf16x8*)&As[buf][(m * 16 + (lane & 15)) * 32 + (lane >> 4) * 8];
#pragma unroll
    for (int n = 0; n < 4; ++n)
      b[n] = *(const bf16x8*)&Bs[buf][(wid * 64 + n * 16 + (lane & 15)) * 32 + (lane >> 4) * 8];
#pragma unroll
    for (int m = 0; m < 4; ++m)
#pragma unroll
      for (int n = 0; n < 4; ++n)
        acc[m][n] = __builtin_amdgcn_mfma_f32_16x16x32_bf16(a[m], b[n], acc[m][n], 0, 0, 0);
    __syncthreads();
    buf ^= 1;
  }

  uint16_t* Pp = P + (uint64_t)s * 2097152;
  const int lr = (lane >> 4) * 4, lc = lane & 15;
#pragma unroll
  for (int m = 0; m < 4; ++m)
#pragma unroll
    for (int n = 0; n < 4; ++n) {
      const int gr = row0 + m * 16 + lr;
      const int gc = wid * 64 + n * 16 + lc;
#pragma unroll
      for (int j = 0; j < 4; ++j)
        Pp[(uint64_t)(gr + j) * 256 + gc] = f2bf(acc[m][n][j]);
    }
}

// ---------------- zw1P: rows = relu(sum_s P[s] (bf16)); Zt = rows @ W1 --------------------
__global__ __launch_bounds__(256) void zw1P(const uint16_t* __restrict__ P,
                                            const float* __restrict__ net,
                                            uint16_t* __restrict__ Zt) {
  __shared__ float Wl[64 * 64];
  __shared__ float rows[64][65];
  const int b = blockIdx.y, n0 = blockIdx.x * 64, tid = threadIdx.x;
  const float* Wsrc = net + 4096;
  for (int i = tid * 4; i < 4096; i += 1024) {
    f32x4 v = *(const f32x4*)(Wsrc + i);
    Wl[i] = v[0]; Wl[i + 1] = v[1]; Wl[i + 2] = v[2]; Wl[i + 3] = v[3];
  }
#pragma unroll
  for (int g = 0; g < 2; ++g) {
    const int idx = (tid + g * 256) * 8;     // 4096 elems = 64 rows x 64 f
    const int r = idx >> 6, f0 = idx & 63;
    const uint16_t* base = P + (uint64_t)(n0 + r) * 256 + b * 64 + f0;
    float acc8[8] = {};
#pragma unroll
    for (int sp = 0; sp < 8; ++sp) {
      u32x4 v = *(const u32x4*)(base + (uint64_t)sp * 2097152);
#pragma unroll
      for (int j = 0; j < 4; ++j) {
        acc8[2 * j]     += bf2f(v[j] & 0xffffu);
        acc8[2 * j + 1] += bf2f(v[j] >> 16);
      }
    }
#pragma unroll
    for (int j = 0; j < 8; ++j) rows[r][f0 + j] = fmaxf(acc8[j], 0.0f);
  }
  __syncthreads();
  const int nl = tid & 63, g0 = (tid >> 6) * 16;
  float s[16];
#pragma unroll
  for (int j = 0; j < 16; ++j) s[j] = 0.f;
  for (int f = 0; f < 64; ++f) {
    float rv = rows[nl][f];
#pragma unroll
    for (int j = 0; j < 16; ++j) s[j] = fmaf(rv, Wl[f * 64 + g0 + j], s[j]);
  }
  uint16_t* dst = Zt + (uint64_t)(b * 64 + g0) * MK + n0 + nl;
#pragma unroll
  for (int j = 0; j < 16; ++j) dst[(uint64_t)j * MK] = f2bf(s[j]);
}

// ---------------- combineF: out = relu(sum_s P[s] (bf16)) -> f32 [4][8192][64] ------------
__global__ __launch_bounds__(256) void combineF(const uint16_t* __restrict__ P,
                                                float* __restrict__ out) {
  const uint64_t e = ((uint64_t)blockIdx.x * 256 + threadIdx.x) * 8;
  float acc8[8] = {};
#pragma unroll
  for (int sp = 0; sp < 8; ++sp) {
    u32x4 v = *(const u32x4*)&P[(uint64_t)sp * 2097152 + e];
#pragma unroll
    for (int j = 0; j < 4; ++j) {
      acc8[2 * j]     += bf2f(v[j] & 0xffffu);
      acc8[2 * j + 1] += bf2f(v[j] >> 16);
    }
  }
  const int m = (int)(e >> 8);
  const int c = (int)(e & 255);
  float* dst = &out[(((uint64_t)(c >> 6)) * MK + m) * 64 + (c & 63)];
  f32x4 w0, w1;
#pragma unroll
  for (int j = 0; j < 4; ++j) { w0[j] = fmaxf(acc8[j], 0.0f); w1[j] = fmaxf(acc8[4 + j], 0.0f); }
  *(f32x4*)dst = w0;
  *(f32x4*)(dst + 4) = w1;
}

extern "C" void kernel_launch(void* const* d_in, const int* in_sizes, int n_in,
                              void* d_out, int out_size, void* d_ws, size_t ws_size,
                              hipStream_t stream) {
  const float* x   = (const float*)d_in[0];
  const float* net = (const float*)d_in[2];
  const float* A   = (const float*)d_in[3];
  float* out = (float*)d_out;

  uint16_t* Ab = (uint16_t*)d_ws;                               // 128 MiB
  uint16_t* Zt = (uint16_t*)((char*)d_ws + 134217728ull);       // 4 MiB
  uint16_t* P  = (uint16_t*)((char*)d_ws + 142606336ull);       // 32 MiB (bf16 [8][8192][256])

  zw0<<<dim3(128, 4), dim3(256), 0, stream>>>(x, net, Zt);
  gemm1<<<dim3(1024), dim3(256), 0, stream>>>(A, Zt, Ab, P);
  zw1P<<<dim3(128, 4), dim3(256), 0, stream>>>(P, net, Zt);
  gemm2<<<dim3(1024), dim3(256), 0, stream>>>(Ab, Zt, P);
  combineF<<<dim3(1024), dim3(256), 0, stream>>>(P, out);
}

// Round 7
// 178.470 us; speedup vs baseline: 1.3225x; 1.3225x over previous
//
#include <hip/hip_runtime.h>
#include <stdint.h>

// B=4, N=8192, F=64, L=2:  z = x; 2x: z = relu(A @ z @ W_l)  ==  relu(A @ (z @ W_l))
// Pipeline (5 dispatches):
//   zw0:      Zt[c=b*64+g][n] = sum_f x[b,n,f] W0[f,g]            (bf16, K-major)
//   gemm1:    P[s][m][c] (bf16) = sum_{k in s} A[m,k] Zt[c][k]    A read NT f32 (r5-proven),
//             cvt->bf16 in-reg, swizzled ds_write + store Ab bf16 (L3-cached for gemm2)
//   zw1P:     rows = relu(sum_s P[s])  (fused combine);  Zt = rows @ W1
//   gemm2:    P[s][m][c] (bf16) = sum_{k in s} Ab[m,k] Zt[c][k]   NEW: BM=128 BN=256 BK=32,
//             512 thr (8 waves 2x4, wave 64x64, acc 64 VGPR), LDS 48 KiB dbuf ->
//             2 blocks/CU co-resident (grid 512 = 64 panels x splitK8, s=bid&7 XCD-pinned),
//             single __syncthreads/tile (cross-block TLP hides the vmcnt drain).
//   combineF: out = relu(sum_s P[s])  -> f32 [4][8192][64]
//
// ws: [0,128Mi) Ab | [128Mi,+4Mi) Zt | [136Mi,+32Mi) P (bf16 [8][8192][256])

#define MK 8192

typedef float f32x4 __attribute__((ext_vector_type(4)));
typedef uint32_t u32x4 __attribute__((ext_vector_type(4)));
typedef uint32_t u32x2 __attribute__((ext_vector_type(2)));
typedef __bf16 bf16x8 __attribute__((ext_vector_type(8)));

__device__ inline uint16_t f2bf(float f) {
  uint32_t u = __builtin_bit_cast(uint32_t, f);
  u += 0x7fffu + ((u >> 16) & 1u);   // RNE (finite randn inputs)
  return (uint16_t)(u >> 16);
}
__device__ inline float bf2f(uint32_t lo16) {
  return __builtin_bit_cast(float, lo16 << 16);
}

#define GLD(src, dstbase)                                                                    \
  __builtin_amdgcn_global_load_lds((const __attribute__((address_space(1))) uint32_t*)(src), \
                                   (__attribute__((address_space(3))) uint32_t*)(dstbase),   \
                                   16, 0, 0)

// ---------------- zw0: Zt = (x @ W0)^T ----------------------------------------------------
__global__ __launch_bounds__(256) void zw0(const float* __restrict__ x,
                                           const float* __restrict__ net,
                                           uint16_t* __restrict__ Zt) {
  __shared__ float Wl[64 * 64];
  __shared__ float rows[64][65];
  const int b = blockIdx.y, n0 = blockIdx.x * 64, tid = threadIdx.x;
  for (int i = tid * 4; i < 4096; i += 1024) {
    f32x4 v = *(const f32x4*)(net + i);
    Wl[i] = v[0]; Wl[i + 1] = v[1]; Wl[i + 2] = v[2]; Wl[i + 3] = v[3];
  }
  const float* src = x + ((uint64_t)b * MK + n0) * 64;
  for (int i = tid * 4; i < 4096; i += 1024) {
    f32x4 v = *(const f32x4*)(src + i);
    int r = i >> 6, f = i & 63;
    rows[r][f] = v[0]; rows[r][f + 1] = v[1]; rows[r][f + 2] = v[2]; rows[r][f + 3] = v[3];
  }
  __syncthreads();
  const int nl = tid & 63, g0 = (tid >> 6) * 16;
  float s[16];
#pragma unroll
  for (int j = 0; j < 16; ++j) s[j] = 0.f;
  for (int f = 0; f < 64; ++f) {
    float rv = rows[nl][f];
#pragma unroll
    for (int j = 0; j < 16; ++j) s[j] = fmaf(rv, Wl[f * 64 + g0 + j], s[j]);
  }
  uint16_t* dst = Zt + (uint64_t)(b * 64 + g0) * MK + n0 + nl;
#pragma unroll
  for (int j = 0; j < 16; ++j) dst[(uint64_t)j * MK] = f2bf(s[j]);
}

// ---------------- gemm1 (r5-proven): A nt-f32 -> cvt -> LDS/Ab; P[s](bf16) = A @ Zt^T -----
__global__ __launch_bounds__(512, 2) void gemm1(const float* __restrict__ Af,
                                                const uint16_t* __restrict__ Bt,
                                                uint16_t* __restrict__ Ab,
                                                uint16_t* __restrict__ P) {
  __shared__ __align__(16) uint16_t As[2][16384];
  __shared__ __align__(16) uint16_t Bs[2][16384];
  const int bid = (int)blockIdx.x;
  const int s = bid & 7, bm = bid >> 3;
  const int row0 = bm * 256, k0 = s * 1024;
  const int tid = threadIdx.x, wid = tid >> 6, lane = tid & 63;
  const int wr = wid >> 2, wc = wid & 3;

  const int lsub = lane >> 3;
  const int ksrc = ((lane & 7) ^ lsub) << 3;
  const uint16_t* gB0 = Bt + (uint64_t)(4 * wid * 8 + lsub) * MK + k0 + ksrc;
  const int lBo = 4 * wid * 512;

  const int arow = (8 * wid) * 4 + (lane >> 4);
  const int acol = (lane & 15) * 4;
  const float* gA0 = Af + (uint64_t)(row0 + arow) * MK + k0 + acol;
  const int koct = (lane & 15) >> 1, krem = (lane & 1) * 4;

  f32x4 acc[8][4] = {};
  f32x4 rv[8];

  auto loadA = [&](int kofs) {
#pragma unroll
    for (int j = 0; j < 8; ++j)
      rv[j] = __builtin_nontemporal_load((const f32x4*)(gA0 + (uint64_t)j * 4 * MK + kofs));
  };
  auto stageA = [&](int buf, int kofs) {
#pragma unroll
    for (int j = 0; j < 8; ++j) {
      const int r = arow + j * 4;
      u32x2 w;
      w[0] = (uint32_t)f2bf(rv[j][0]) | ((uint32_t)f2bf(rv[j][1]) << 16);
      w[1] = (uint32_t)f2bf(rv[j][2]) | ((uint32_t)f2bf(rv[j][3]) << 16);
      *(u32x2*)&As[buf][r * 64 + ((koct ^ (r & 7)) << 3) + krem] = w;
      *(u32x2*)(Ab + (uint64_t)(row0 + r) * MK + k0 + kofs + acol) = w;
    }
  };

  loadA(0);
#pragma unroll
  for (int j = 0; j < 4; ++j) GLD(gB0 + (uint64_t)j * 8 * MK, &Bs[0][lBo + j * 512]);
  stageA(0, 0);
  __syncthreads();

  int buf = 0;
  for (int t = 0; t < 16; ++t) {
    const int nxt = (t + 1) * 64;
    if (t < 15) {
      loadA(nxt);
#pragma unroll
      for (int j = 0; j < 4; ++j) GLD(gB0 + (uint64_t)j * 8 * MK + nxt, &Bs[buf ^ 1][lBo + j * 512]);
    }
#pragma unroll
    for (int kk = 0; kk < 2; ++kk) {
      const int kb = kk * 4 + (lane >> 4);
      bf16x8 a[8], b[4];
#pragma unroll
      for (int mi = 0; mi < 8; ++mi) {
        const int r = wr * 128 + mi * 16 + (lane & 15);
        a[mi] = *(const bf16x8*)&As[buf][r * 64 + ((kb ^ (r & 7)) << 3)];
      }
#pragma unroll
      for (int n = 0; n < 4; ++n) {
        const int r = wc * 64 + n * 16 + (lane & 15);
        b[n] = *(const bf16x8*)&Bs[buf][r * 64 + ((kb ^ (r & 7)) << 3)];
      }
#pragma unroll
      for (int mi = 0; mi < 8; ++mi)
#pragma unroll
        for (int n = 0; n < 4; ++n)
          acc[mi][n] = __builtin_amdgcn_mfma_f32_16x16x32_bf16(a[mi], b[n], acc[mi][n], 0, 0, 0);
    }
    if (t < 15) stageA(buf ^ 1, nxt);
    __syncthreads();
    buf ^= 1;
  }

  uint16_t* Pp = P + (uint64_t)s * 2097152;
  const int lr = (lane >> 4) * 4, lc = lane & 15;
#pragma unroll
  for (int mi = 0; mi < 8; ++mi)
#pragma unroll
    for (int n = 0; n < 4; ++n) {
      const int gr = row0 + wr * 128 + mi * 16 + lr;
      const int gc = wc * 64 + n * 16 + lc;
#pragma unroll
      for (int j = 0; j < 4; ++j)
        Pp[(uint64_t)(gr + j) * 256 + gc] = f2bf(acc[mi][n][j]);
    }
}

// ---------------- gemm2: BM=128 BN=256 BK=32, 512thr, 2 blocks/CU -------------------------
// Staging: A 1 GLD/thread, B 2 GLD/thread (chunk = 16 rows x 32k = 1KB, linear LDS,
// frag reads bijective per chunk -> conflict-free). Single __syncthreads per tile.
__global__ __launch_bounds__(512, 2) void gemm2(const uint16_t* __restrict__ Ab,
                                                const uint16_t* __restrict__ Bt,
                                                uint16_t* __restrict__ P) {
  __shared__ __align__(16) uint16_t As[2][4096];   // [128r][32k] bf16, 8 KB/buf
  __shared__ __align__(16) uint16_t Bs[2][8192];   // [256r][32k] bf16, 16 KB/buf
  const int bid = (int)blockIdx.x;
  const int s = bid & 7, bm = bid >> 3;            // 64 m-panels x splitK8, XCD-pinned chunk
  const int row0 = bm * 128, k0 = s * 1024;
  const int tid = threadIdx.x, wid = tid >> 6, lane = tid & 63;
  const int wr = wid >> 2, wc = wid & 3;           // 2x4 waves, wave tile 64x64

  // staging: lane l of wave w -> row w*16 + (l>>2), k-octet (l&3)*8; LDS = tid*8 (linear)
  const int crow = lane >> 2, coct = (lane & 3) * 8;
  const uint16_t* gA = Ab + (uint64_t)(row0 + wid * 16 + crow) * MK + k0 + coct;
  const uint16_t* gB0 = Bt + (uint64_t)(wid * 16 + crow) * MK + k0 + coct;          // rows 0-127
  const uint16_t* gB1 = Bt + (uint64_t)(128 + wid * 16 + crow) * MK + k0 + coct;    // rows 128-255
  const int lA = wid * 512, lB0 = wid * 512, lB1 = 4096 + wid * 512;

  f32x4 acc[4][4] = {};

  // prologue: tile 0 -> buf 0
  GLD(gA, &As[0][lA]);
  GLD(gB0, &Bs[0][lB0]);
  GLD(gB1, &Bs[0][lB1]);
  __syncthreads();

  int buf = 0;
  for (int t = 0; t < 32; ++t) {
    if (t < 31) {
      const int nxt = (t + 1) * 32;
      GLD(gA + nxt, &As[buf ^ 1][lA]);
      GLD(gB0 + nxt, &Bs[buf ^ 1][lB0]);
      GLD(gB1 + nxt, &Bs[buf ^ 1][lB1]);
    }
    bf16x8 a[4], b[4];
#pragma unroll
    for (int m = 0; m < 4; ++m)
      a[m] = *(const bf16x8*)&As[buf][(wr * 64 + m * 16 + (lane & 15)) * 32 + (lane >> 4) * 8];
#pragma unroll
    for (int n = 0; n < 4; ++n)
      b[n] = *(const bf16x8*)&Bs[buf][(wc * 64 + n * 16 + (lane & 15)) * 32 + (lane >> 4) * 8];
#pragma unroll
    for (int m = 0; m < 4; ++m)
#pragma unroll
      for (int n = 0; n < 4; ++n)
        acc[m][n] = __builtin_amdgcn_mfma_f32_16x16x32_bf16(a[m], b[n], acc[m][n], 0, 0, 0);
    __syncthreads();
    buf ^= 1;
  }

  uint16_t* Pp = P + (uint64_t)s * 2097152;
  const int lr = (lane >> 4) * 4, lc = lane & 15;
#pragma unroll
  for (int m = 0; m < 4; ++m)
#pragma unroll
    for (int n = 0; n < 4; ++n) {
      const int gr = row0 + wr * 64 + m * 16 + lr;
      const int gc = wc * 64 + n * 16 + lc;
#pragma unroll
      for (int j = 0; j < 4; ++j)
        Pp[(uint64_t)(gr + j) * 256 + gc] = f2bf(acc[m][n][j]);
    }
}

// ---------------- zw1P: rows = relu(sum_s P[s] (bf16)); Zt = rows @ W1 --------------------
__global__ __launch_bounds__(256) void zw1P(const uint16_t* __restrict__ P,
                                            const float* __restrict__ net,
                                            uint16_t* __restrict__ Zt) {
  __shared__ float Wl[64 * 64];
  __shared__ float rows[64][65];
  const int b = blockIdx.y, n0 = blockIdx.x * 64, tid = threadIdx.x;
  const float* Wsrc = net + 4096;
  for (int i = tid * 4; i < 4096; i += 1024) {
    f32x4 v = *(const f32x4*)(Wsrc + i);
    Wl[i] = v[0]; Wl[i + 1] = v[1]; Wl[i + 2] = v[2]; Wl[i + 3] = v[3];
  }
#pragma unroll
  for (int g = 0; g < 2; ++g) {
    const int idx = (tid + g * 256) * 8;     // 4096 elems = 64 rows x 64 f
    const int r = idx >> 6, f0 = idx & 63;
    const uint16_t* base = P + (uint64_t)(n0 + r) * 256 + b * 64 + f0;
    float acc8[8] = {};
#pragma unroll
    for (int sp = 0; sp < 8; ++sp) {
      u32x4 v = *(const u32x4*)(base + (uint64_t)sp * 2097152);
#pragma unroll
      for (int j = 0; j < 4; ++j) {
        acc8[2 * j]     += bf2f(v[j] & 0xffffu);
        acc8[2 * j + 1] += bf2f(v[j] >> 16);
      }
    }
#pragma unroll
    for (int j = 0; j < 8; ++j) rows[r][f0 + j] = fmaxf(acc8[j], 0.0f);
  }
  __syncthreads();
  const int nl = tid & 63, g0 = (tid >> 6) * 16;
  float s[16];
#pragma unroll
  for (int j = 0; j < 16; ++j) s[j] = 0.f;
  for (int f = 0; f < 64; ++f) {
    float rv = rows[nl][f];
#pragma unroll
    for (int j = 0; j < 16; ++j) s[j] = fmaf(rv, Wl[f * 64 + g0 + j], s[j]);
  }
  uint16_t* dst = Zt + (uint64_t)(b * 64 + g0) * MK + n0 + nl;
#pragma unroll
  for (int j = 0; j < 16; ++j) dst[(uint64_t)j * MK] = f2bf(s[j]);
}

// ---------------- combineF: out = relu(sum_s P[s] (bf16)) -> f32 [4][8192][64] ------------
__global__ __launch_bounds__(256) void combineF(const uint16_t* __restrict__ P,
                                                float* __restrict__ out) {
  const uint64_t e = ((uint64_t)blockIdx.x * 256 + threadIdx.x) * 8;
  float acc8[8] = {};
#pragma unroll
  for (int sp = 0; sp < 8; ++sp) {
    u32x4 v = *(const u32x4*)&P[(uint64_t)sp * 2097152 + e];
#pragma unroll
    for (int j = 0; j < 4; ++j) {
      acc8[2 * j]     += bf2f(v[j] & 0xffffu);
      acc8[2 * j + 1] += bf2f(v[j] >> 16);
    }
  }
  const int m = (int)(e >> 8);
  const int c = (int)(e & 255);
  float* dst = &out[(((uint64_t)(c >> 6)) * MK + m) * 64 + (c & 63)];
  f32x4 w0, w1;
#pragma unroll
  for (int j = 0; j < 4; ++j) { w0[j] = fmaxf(acc8[j], 0.0f); w1[j] = fmaxf(acc8[4 + j], 0.0f); }
  *(f32x4*)dst = w0;
  *(f32x4*)(dst + 4) = w1;
}

extern "C" void kernel_launch(void* const* d_in, const int* in_sizes, int n_in,
                              void* d_out, int out_size, void* d_ws, size_t ws_size,
                              hipStream_t stream) {
  const float* x   = (const float*)d_in[0];
  const float* net = (const float*)d_in[2];
  const float* A   = (const float*)d_in[3];
  float* out = (float*)d_out;

  uint16_t* Ab = (uint16_t*)d_ws;                               // 128 MiB
  uint16_t* Zt = (uint16_t*)((char*)d_ws + 134217728ull);       // 4 MiB
  uint16_t* P  = (uint16_t*)((char*)d_ws + 142606336ull);       // 32 MiB (bf16 [8][8192][256])

  zw0<<<dim3(128, 4), dim3(256), 0, stream>>>(x, net, Zt);
  gemm1<<<dim3(256), dim3(512), 0, stream>>>(A, Zt, Ab, P);
  zw1P<<<dim3(128, 4), dim3(256), 0, stream>>>(P, net, Zt);
  gemm2<<<dim3(512), dim3(512), 0, stream>>>(Ab, Zt, P);
  combineF<<<dim3(1024), dim3(256), 0, stream>>>(P, out);
}

// Round 8
// 175.269 us; speedup vs baseline: 1.3467x; 1.0183x over previous
//
#include <hip/hip_runtime.h>
#include <stdint.h>

// B=4, N=8192, F=64, L=2:  z = x; 2x: z = relu(A @ z @ W_l)  ==  relu(A @ (z @ W_l))
// Pipeline (5 dispatches):
//   zw0:      Zt[c=b*64+g][n] = sum_f x[b,n,f] W0[f,g]            (bf16, K-major)
//   gemm1:    P[s][m][c] (bf16) = sum_{k in s} A[m,k] Zt[c][k]    A read NT f32 (r5-proven),
//             cvt->bf16 in-reg, swizzled ds_write + store Ab bf16 (L3-cached for gemm2)
//   zw1P:     rows = relu(sum_s P[s])  (fused combine);  Zt = rows @ W1
//   gemm2:    8-PHASE m201-template port: 256x256 tile BK=64, 2 K-tiles/iter,
//             per-phase {ds_read | 1 half-tile GLD | bar | lgkm0 | setprio 16xMFMA | bar},
//             vmcnt(4) at P4/P8 only (never 0), splitK=8, grid 256 = 1 block/CU.
//   combineF: out = relu(sum_s P[s])  -> f32 [4][8192][64]
//
// ws: [0,128Mi) Ab | [128Mi,+4Mi) Zt | [136Mi,+32Mi) P (bf16 [8][8192][256])

#define MK 8192

typedef float f32x4 __attribute__((ext_vector_type(4)));
typedef uint32_t u32x4 __attribute__((ext_vector_type(4)));
typedef uint32_t u32x2 __attribute__((ext_vector_type(2)));
typedef __bf16 bf16x8 __attribute__((ext_vector_type(8)));

__device__ inline uint16_t f2bf(float f) {
  uint32_t u = __builtin_bit_cast(uint32_t, f);
  u += 0x7fffu + ((u >> 16) & 1u);   // RNE (finite randn inputs)
  return (uint16_t)(u >> 16);
}
__device__ inline float bf2f(uint32_t lo16) {
  return __builtin_bit_cast(float, lo16 << 16);
}

#define GLD(src, dstbase)                                                                    \
  __builtin_amdgcn_global_load_lds((const __attribute__((address_space(1))) uint32_t*)(src), \
                                   (__attribute__((address_space(3))) uint32_t*)(dstbase),   \
                                   16, 0, 0)
#define BAR __builtin_amdgcn_s_barrier()
#define LGKM0                                          \
  do {                                                 \
    asm volatile("s_waitcnt lgkmcnt(0)" ::: "memory"); \
    __builtin_amdgcn_sched_barrier(0);                 \
  } while (0)

// ---------------- zw0: Zt = (x @ W0)^T ----------------------------------------------------
__global__ __launch_bounds__(256) void zw0(const float* __restrict__ x,
                                           const float* __restrict__ net,
                                           uint16_t* __restrict__ Zt) {
  __shared__ float Wl[64 * 64];
  __shared__ float rows[64][65];
  const int b = blockIdx.y, n0 = blockIdx.x * 64, tid = threadIdx.x;
  for (int i = tid * 4; i < 4096; i += 1024) {
    f32x4 v = *(const f32x4*)(net + i);
    Wl[i] = v[0]; Wl[i + 1] = v[1]; Wl[i + 2] = v[2]; Wl[i + 3] = v[3];
  }
  const float* src = x + ((uint64_t)b * MK + n0) * 64;
  for (int i = tid * 4; i < 4096; i += 1024) {
    f32x4 v = *(const f32x4*)(src + i);
    int r = i >> 6, f = i & 63;
    rows[r][f] = v[0]; rows[r][f + 1] = v[1]; rows[r][f + 2] = v[2]; rows[r][f + 3] = v[3];
  }
  __syncthreads();
  const int nl = tid & 63, g0 = (tid >> 6) * 16;
  float s[16];
#pragma unroll
  for (int j = 0; j < 16; ++j) s[j] = 0.f;
  for (int f = 0; f < 64; ++f) {
    float rv = rows[nl][f];
#pragma unroll
    for (int j = 0; j < 16; ++j) s[j] = fmaf(rv, Wl[f * 64 + g0 + j], s[j]);
  }
  uint16_t* dst = Zt + (uint64_t)(b * 64 + g0) * MK + n0 + nl;
#pragma unroll
  for (int j = 0; j < 16; ++j) dst[(uint64_t)j * MK] = f2bf(s[j]);
}

// ---------------- gemm1 (r5-proven): A nt-f32 -> cvt -> LDS/Ab; P[s](bf16) = A @ Zt^T -----
__global__ __launch_bounds__(512, 2) void gemm1(const float* __restrict__ Af,
                                                const uint16_t* __restrict__ Bt,
                                                uint16_t* __restrict__ Ab,
                                                uint16_t* __restrict__ P) {
  __shared__ __align__(16) uint16_t As[2][16384];
  __shared__ __align__(16) uint16_t Bs[2][16384];
  const int bid = (int)blockIdx.x;
  const int s = bid & 7, bm = bid >> 3;
  const int row0 = bm * 256, k0 = s * 1024;
  const int tid = threadIdx.x, wid = tid >> 6, lane = tid & 63;
  const int wr = wid >> 2, wc = wid & 3;

  const int lsub = lane >> 3;
  const int ksrc = ((lane & 7) ^ lsub) << 3;
  const uint16_t* gB0 = Bt + (uint64_t)(4 * wid * 8 + lsub) * MK + k0 + ksrc;
  const int lBo = 4 * wid * 512;

  const int arow = (8 * wid) * 4 + (lane >> 4);
  const int acol = (lane & 15) * 4;
  const float* gA0 = Af + (uint64_t)(row0 + arow) * MK + k0 + acol;
  const int koct = (lane & 15) >> 1, krem = (lane & 1) * 4;

  f32x4 acc[8][4] = {};
  f32x4 rv[8];

  auto loadA = [&](int kofs) {
#pragma unroll
    for (int j = 0; j < 8; ++j)
      rv[j] = __builtin_nontemporal_load((const f32x4*)(gA0 + (uint64_t)j * 4 * MK + kofs));
  };
  auto stageA = [&](int buf, int kofs) {
#pragma unroll
    for (int j = 0; j < 8; ++j) {
      const int r = arow + j * 4;
      u32x2 w;
      w[0] = (uint32_t)f2bf(rv[j][0]) | ((uint32_t)f2bf(rv[j][1]) << 16);
      w[1] = (uint32_t)f2bf(rv[j][2]) | ((uint32_t)f2bf(rv[j][3]) << 16);
      *(u32x2*)&As[buf][r * 64 + ((koct ^ (r & 7)) << 3) + krem] = w;
      *(u32x2*)(Ab + (uint64_t)(row0 + r) * MK + k0 + kofs + acol) = w;
    }
  };

  loadA(0);
#pragma unroll
  for (int j = 0; j < 4; ++j) GLD(gB0 + (uint64_t)j * 8 * MK, &Bs[0][lBo + j * 512]);
  stageA(0, 0);
  __syncthreads();

  int buf = 0;
  for (int t = 0; t < 16; ++t) {
    const int nxt = (t + 1) * 64;
    if (t < 15) {
      loadA(nxt);
#pragma unroll
      for (int j = 0; j < 4; ++j) GLD(gB0 + (uint64_t)j * 8 * MK + nxt, &Bs[buf ^ 1][lBo + j * 512]);
    }
#pragma unroll
    for (int kk = 0; kk < 2; ++kk) {
      const int kb = kk * 4 + (lane >> 4);
      bf16x8 a[8], b[4];
#pragma unroll
      for (int mi = 0; mi < 8; ++mi) {
        const int r = wr * 128 + mi * 16 + (lane & 15);
        a[mi] = *(const bf16x8*)&As[buf][r * 64 + ((kb ^ (r & 7)) << 3)];
      }
#pragma unroll
      for (int n = 0; n < 4; ++n) {
        const int r = wc * 64 + n * 16 + (lane & 15);
        b[n] = *(const bf16x8*)&Bs[buf][r * 64 + ((kb ^ (r & 7)) << 3)];
      }
#pragma unroll
      for (int mi = 0; mi < 8; ++mi)
#pragma unroll
        for (int n = 0; n < 4; ++n)
          acc[mi][n] = __builtin_amdgcn_mfma_f32_16x16x32_bf16(a[mi], b[n], acc[mi][n], 0, 0, 0);
    }
    if (t < 15) stageA(buf ^ 1, nxt);
    __syncthreads();
    buf ^= 1;
  }

  uint16_t* Pp = P + (uint64_t)s * 2097152;
  const int lr = (lane >> 4) * 4, lc = lane & 15;
#pragma unroll
  for (int mi = 0; mi < 8; ++mi)
#pragma unroll
    for (int n = 0; n < 4; ++n) {
      const int gr = row0 + wr * 128 + mi * 16 + lr;
      const int gc = wc * 64 + n * 16 + lc;
#pragma unroll
      for (int j = 0; j < 4; ++j)
        Pp[(uint64_t)(gr + j) * 256 + gc] = f2bf(acc[mi][n][j]);
    }
}

// ---------------- gemm2: 8-phase template (m201 port), 256x256 BK=64, splitK=8 ------------
__global__ __launch_bounds__(512, 2) void gemm2(const uint16_t* __restrict__ Ab,
                                                const uint16_t* __restrict__ Bt,
                                                uint16_t* __restrict__ P) {
  __shared__ __align__(16) uint16_t AL[2][16384];   // [buf][256r x 64k] 32 KB each
  __shared__ __align__(16) uint16_t BL[2][16384];
  const int bid = (int)blockIdx.x;
  const int s = bid & 7, bm = bid >> 3;
  const int row0 = bm * 256, k0 = s * 1024;
  const int tid = threadIdx.x, wid = tid >> 6, lane = tid & 63;
  const int wr = wid >> 2, wc = wid & 3;

  const int kst = ((lane & 7) ^ (lane >> 3)) << 3;  // pre-swizzled src k-octet
  const int srow = lane >> 3;                        // row within 8-row chunk
  const int fr = lane & 15, fk = lane >> 4;

  f32x4 acc[8][4] = {};

  // stage one half-tile (128r x 64k): 2 chunks/wave, chunk = 8r x 64k = 1 KB
  auto stgA = [&](int bi, int half, int t) {
#pragma unroll
    for (int e = 0; e < 2; ++e) {
      const int c = 2 * wid + e;
      GLD(Ab + (uint64_t)(row0 + half * 128 + c * 8 + srow) * MK + k0 + t * 64 + kst,
          &AL[bi][half * 8192 + c * 512]);
    }
  };
  auto stgB = [&](int bi, int half, int t) {
#pragma unroll
    for (int e = 0; e < 2; ++e) {
      const int c = 2 * wid + e;
      GLD(Bt + (uint64_t)(half * 128 + c * 8 + srow) * MK + k0 + t * 64 + kst,
          &BL[bi][half * 8192 + c * 512]);
    }
  };

  bf16x8 b[4][2], a[2][2];
  auto rdB = [&](int bi) {
    const uint16_t* L = bi ? BL[1] : BL[0];
#pragma unroll
    for (int n = 0; n < 4; ++n)
#pragma unroll
      for (int kk = 0; kk < 2; ++kk) {
        const int r = wc * 64 + n * 16 + fr;
        b[n][kk] = *(const bf16x8*)&L[r * 64 + (((kk * 4 + fk) ^ (r & 7)) << 3)];
      }
  };
  auto rdA = [&](int bi, int q) {
    const uint16_t* L = bi ? AL[1] : AL[0];
#pragma unroll
    for (int i = 0; i < 2; ++i)
#pragma unroll
      for (int kk = 0; kk < 2; ++kk) {
        const int r = wr * 128 + (2 * q + i) * 16 + fr;
        a[i][kk] = *(const bf16x8*)&L[r * 64 + (((kk * 4 + fk) ^ (r & 7)) << 3)];
      }
  };
  auto mfma16 = [&](int q) {
    __builtin_amdgcn_s_setprio(1);
#pragma unroll
    for (int kk = 0; kk < 2; ++kk)
#pragma unroll
      for (int i = 0; i < 2; ++i)
#pragma unroll
        for (int n = 0; n < 4; ++n)
          acc[2 * q + i][n] =
              __builtin_amdgcn_mfma_f32_16x16x32_bf16(a[i][kk], b[n][kk], acc[2 * q + i][n], 0, 0, 0);
    __builtin_amdgcn_s_setprio(0);
  };

  // prologue: T0 -> A0,B0; T1's B -> B1  (12 loads; vmcnt(4) keeps B1 in flight)
  stgA(0, 0, 0); stgA(0, 1, 0);
  stgB(0, 0, 0); stgB(0, 1, 0);
  stgB(1, 0, 1); stgB(1, 1, 1);
  asm volatile("s_waitcnt vmcnt(4)" ::: "memory");
  BAR;

  for (int j = 0; j < 8; ++j) {
    const int t1 = 2 * j + 1;
    const int t2 = (2 * j + 2 < 16) ? 2 * j + 2 : 15;
    const int t3 = (2 * j + 3 < 16) ? 2 * j + 3 : 15;

    // ---- P1-P4: T(2j) from buf0; stage A1<-A(t1), B0<-B(t2) ----
    rdB(0); rdA(0, 0); stgA(1, 0, t1);
    asm volatile("s_waitcnt lgkmcnt(8)" ::: "memory");
    BAR; LGKM0; mfma16(0); BAR;

    rdA(0, 1); stgA(1, 1, t1);
    BAR; LGKM0; mfma16(1); BAR;

    rdA(0, 2); stgB(0, 0, t2);
    BAR; LGKM0; mfma16(2); BAR;

    rdA(0, 3); stgB(0, 1, t2);
    asm volatile("s_waitcnt vmcnt(4)" ::: "memory");   // A1(t1)+B1(t1) landed for P5
    BAR; LGKM0; mfma16(3); BAR;

    // ---- P5-P8: T(2j+1) from buf1; stage A0<-A(t2), B1<-B(t3) ----
    rdB(1); rdA(1, 0); stgA(0, 0, t2);
    asm volatile("s_waitcnt lgkmcnt(8)" ::: "memory");
    BAR; LGKM0; mfma16(0); BAR;

    rdA(1, 1); stgA(0, 1, t2);
    BAR; LGKM0; mfma16(1); BAR;

    rdA(1, 2); stgB(1, 0, t3);
    BAR; LGKM0; mfma16(2); BAR;

    rdA(1, 3); stgB(1, 1, t3);
    asm volatile("s_waitcnt vmcnt(4)" ::: "memory");   // A0(t2)+B0(t2) landed for next P1
    BAR; LGKM0; mfma16(3); BAR;
  }

  uint16_t* Pp = P + (uint64_t)s * 2097152;
  const int lr = (lane >> 4) * 4, lc = lane & 15;
#pragma unroll
  for (int mi = 0; mi < 8; ++mi)
#pragma unroll
    for (int n = 0; n < 4; ++n) {
      const int gr = row0 + wr * 128 + mi * 16 + lr;
      const int gc = wc * 64 + n * 16 + lc;
#pragma unroll
      for (int j = 0; j < 4; ++j)
        Pp[(uint64_t)(gr + j) * 256 + gc] = f2bf(acc[mi][n][j]);
    }
}

// ---------------- zw1P: rows = relu(sum_s P[s] (bf16)); Zt = rows @ W1 --------------------
__global__ __launch_bounds__(256) void zw1P(const uint16_t* __restrict__ P,
                                            const float* __restrict__ net,
                                            uint16_t* __restrict__ Zt) {
  __shared__ float Wl[64 * 64];
  __shared__ float rows[64][65];
  const int b = blockIdx.y, n0 = blockIdx.x * 64, tid = threadIdx.x;
  const float* Wsrc = net + 4096;
  for (int i = tid * 4; i < 4096; i += 1024) {
    f32x4 v = *(const f32x4*)(Wsrc + i);
    Wl[i] = v[0]; Wl[i + 1] = v[1]; Wl[i + 2] = v[2]; Wl[i + 3] = v[3];
  }
#pragma unroll
  for (int g = 0; g < 2; ++g) {
    const int idx = (tid + g * 256) * 8;     // 4096 elems = 64 rows x 64 f
    const int r = idx >> 6, f0 = idx & 63;
    const uint16_t* base = P + (uint64_t)(n0 + r) * 256 + b * 64 + f0;
    float acc8[8] = {};
#pragma unroll
    for (int sp = 0; sp < 8; ++sp) {
      u32x4 v = *(const u32x4*)(base + (uint64_t)sp * 2097152);
#pragma unroll
      for (int j = 0; j < 4; ++j) {
        acc8[2 * j]     += bf2f(v[j] & 0xffffu);
        acc8[2 * j + 1] += bf2f(v[j] >> 16);
      }
    }
#pragma unroll
    for (int j = 0; j < 8; ++j) rows[r][f0 + j] = fmaxf(acc8[j], 0.0f);
  }
  __syncthreads();
  const int nl = tid & 63, g0 = (tid >> 6) * 16;
  float s[16];
#pragma unroll
  for (int j = 0; j < 16; ++j) s[j] = 0.f;
  for (int f = 0; f < 64; ++f) {
    float rv = rows[nl][f];
#pragma unroll
    for (int j = 0; j < 16; ++j) s[j] = fmaf(rv, Wl[f * 64 + g0 + j], s[j]);
  }
  uint16_t* dst = Zt + (uint64_t)(b * 64 + g0) * MK + n0 + nl;
#pragma unroll
  for (int j = 0; j < 16; ++j) dst[(uint64_t)j * MK] = f2bf(s[j]);
}

// ---------------- combineF: out = relu(sum_s P[s] (bf16)) -> f32 [4][8192][64] ------------
__global__ __launch_bounds__(256) void combineF(const uint16_t* __restrict__ P,
                                                float* __restrict__ out) {
  const uint64_t e = ((uint64_t)blockIdx.x * 256 + threadIdx.x) * 8;
  float acc8[8] = {};
#pragma unroll
  for (int sp = 0; sp < 8; ++sp) {
    u32x4 v = *(const u32x4*)&P[(uint64_t)sp * 2097152 + e];
#pragma unroll
    for (int j = 0; j < 4; ++j) {
      acc8[2 * j]     += bf2f(v[j] & 0xffffu);
      acc8[2 * j + 1] += bf2f(v[j] >> 16);
    }
  }
  const int m = (int)(e >> 8);
  const int c = (int)(e & 255);
  float* dst = &out[(((uint64_t)(c >> 6)) * MK + m) * 64 + (c & 63)];
  f32x4 w0, w1;
#pragma unroll
  for (int j = 0; j < 4; ++j) { w0[j] = fmaxf(acc8[j], 0.0f); w1[j] = fmaxf(acc8[4 + j], 0.0f); }
  *(f32x4*)dst = w0;
  *(f32x4*)(dst + 4) = w1;
}

extern "C" void kernel_launch(void* const* d_in, const int* in_sizes, int n_in,
                              void* d_out, int out_size, void* d_ws, size_t ws_size,
                              hipStream_t stream) {
  const float* x   = (const float*)d_in[0];
  const float* net = (const float*)d_in[2];
  const float* A   = (const float*)d_in[3];
  float* out = (float*)d_out;

  uint16_t* Ab = (uint16_t*)d_ws;                               // 128 MiB
  uint16_t* Zt = (uint16_t*)((char*)d_ws + 134217728ull);       // 4 MiB
  uint16_t* P  = (uint16_t*)((char*)d_ws + 142606336ull);       // 32 MiB (bf16 [8][8192][256])

  zw0<<<dim3(128, 4), dim3(256), 0, stream>>>(x, net, Zt);
  gemm1<<<dim3(256), dim3(512), 0, stream>>>(A, Zt, Ab, P);
  zw1P<<<dim3(128, 4), dim3(256), 0, stream>>>(P, net, Zt);
  gemm2<<<dim3(256), dim3(512), 0, stream>>>(Ab, Zt, P);
  combineF<<<dim3(1024), dim3(256), 0, stream>>>(P, out);
}